// Round 7
// baseline (291.086 us; speedup 1.0000x reference)
//
#include <hip/hip_runtime.h>
#include <hip/hip_fp16.h>
#include <math.h>

#define ELL_CAP 48
#define NBUCK 391   // ceil(100000/256)
#define SLB 256     // bucket-writer blocks
#define SLICE 48    // per-(block,bucket) slice capacity (mean 12, P(>=48)~3e-15)

typedef _Float16 half8 __attribute__((ext_vector_type(8)));
typedef float floatx4 __attribute__((ext_vector_type(4)));

// ---------------- small helpers ----------------

__device__ __forceinline__ __half2 u2h(unsigned u) {
  __half2 h; __builtin_memcpy(&h, &u, 4); return h;
}
__device__ __forceinline__ unsigned h2u(__half2 h) {
  unsigned u; __builtin_memcpy(&u, &h, 4); return u;
}

// ------ Phase A: slice-partitioned bucket scatter, SINGLE sweep --------------

__global__ __launch_bounds__(1024) void k_bucket(const int* __restrict__ src,
                                                 const int* __restrict__ dst,
                                                 int* __restrict__ hist_g,
                                                 int* __restrict__ buckets, int E) {
  __shared__ int histL[NBUCK];
  const int tid = threadIdx.x, b = blockIdx.x;
  for (int i = tid; i < NBUCK; i += 1024) histL[i] = 0;
  __syncthreads();

  const long s0 = (long)b * E / SLB, s1 = (long)(b + 1) * E / SLB;
  for (long e = s0 + tid; e < s1; e += 1024) {
    int s = src[e], d = dst[e];
    int bi = d >> 8;
    int pos = atomicAdd(&histL[bi], 1);
    if (pos < SLICE)
      buckets[(long)bi * (SLB * SLICE) + b * SLICE + pos] = ((d & 255) << 24) | s;
  }
  __syncthreads();

  for (int i = tid; i < NBUCK; i += 1024) hist_g[i * SLB + b] = min(histL[i], SLICE);
}

// ------- Phase B: per-bucket ELL build in LDS from 256 slices (int4 reads) ---

__global__ __launch_bounds__(512) void k_ellbuild(const int* __restrict__ buckets,
                                                  const int* __restrict__ hist_g,
                                                  int* __restrict__ cnt,
                                                  int* __restrict__ ell,
                                                  float* __restrict__ dinv, int n) {
  __shared__ int cnt_l[256];
  __shared__ int ell_l[256 * ELL_CAP];
  __shared__ int cslice[SLB];
  __shared__ unsigned char lim4[256];
  const int b = blockIdx.x, tid = threadIdx.x;
  if (tid < 256) cnt_l[tid] = 0;
  if (tid < SLB) cslice[tid] = hist_g[b * SLB + tid];
  __syncthreads();

  const int s = tid >> 1;
  const int m = cslice[s];
  const int4* bk4 = (const int4*)(buckets + (long)b * (SLB * SLICE) + s * SLICE);
  const int nq = (m + 3) >> 2;
  for (int j = (tid & 1); j < nq; j += 2) {
    int4 q = bk4[j];
    const int e0 = j * 4;
    int v[4] = {q.x, q.y, q.z, q.w};
#pragma unroll
    for (int k = 0; k < 4; ++k) {
      if (e0 + k < m) {
        int p = v[k];
        int ld = ((unsigned)p) >> 24;
        int pos = atomicAdd(&cnt_l[ld], 1);
        if (pos < ELL_CAP) ell_l[ld * ELL_CAP + pos] = p & 0xFFFFFF;
      }
    }
  }
  __syncthreads();

  const int d0 = b << 8;
  const int node = d0 + tid;
  const int rows = min(256, n - d0);
  if (tid < rows) {
    int c = cnt_l[tid];
    if (c > ELL_CAP) c = ELL_CAP;
    cnt[node] = c;
    dinv[node] = 1.0f / sqrtf((float)(c + 1));  // +1 self-loop, precise
    lim4[tid] = (unsigned char)((c + 3) >> 2);
  }
  __syncthreads();

  int4* dst4 = (int4*)(ell + (long)d0 * ELL_CAP);
  const int4* src4 = (const int4*)ell_l;
  const int tot = rows * 12;
  for (int i = tid; i < tot; i += 512) {
    int r = i / 12, w = i - r * 12;
    if (w < (int)lim4[r]) dst4[i] = src4[i];
  }
}

// ---------------- MFMA GEMM (layer 0): hs0 = dinv * (x @ W0), fp16 ----------

__global__ __launch_bounds__(256) void k_gemm_mfma128(const float* __restrict__ Xf,
                                                      const float* __restrict__ W,
                                                      const float* __restrict__ dinv,
                                                      __half* __restrict__ out,
                                                      __half* __restrict__ zrowA,
                                                      __half* __restrict__ zrowB, int n) {
  constexpr int K = 128, SP = K + 8, NS = K / 32;
  __shared__ __half Wl[64 * SP];
  const int tx = threadIdx.x;

  if (blockIdx.x == 0 && tx < 64) { zrowA[tx] = __float2half(0.f); zrowB[tx] = __float2half(0.f); }

  for (int idx = tx; idx < (K / 2) * 64; idx += 256) {
    int k2 = idx >> 6, col = idx & 63;
    __half2 h = __floats2half2_rn(W[(2 * k2) * 64 + col], W[(2 * k2 + 1) * 64 + col]);
    *(__half2*)&Wl[col * SP + 2 * k2] = h;
  }
  __syncthreads();

  const int lane = tx & 63;
  const int l15 = lane & 15;
  const int quad = lane >> 4;
  const long base = (long)blockIdx.x * 64 + (tx >> 6) * 16;

  long arow = base + l15;
  if (arow >= n) arow = n - 1;  // clamp; stores predicated

  half8 afrag[NS];
#pragma unroll
  for (int s = 0; s < NS; ++s) {
    float4 lo = *(const float4*)&Xf[arow * K + s * 32 + quad * 8];
    float4 hi = *(const float4*)&Xf[arow * K + s * 32 + quad * 8 + 4];
    half8 a;
    a[0] = (_Float16)lo.x; a[1] = (_Float16)lo.y;
    a[2] = (_Float16)lo.z; a[3] = (_Float16)lo.w;
    a[4] = (_Float16)hi.x; a[5] = (_Float16)hi.y;
    a[6] = (_Float16)hi.z; a[7] = (_Float16)hi.w;
    afrag[s] = a;
  }

  floatx4 acc[4];
#pragma unroll
  for (int t = 0; t < 4; ++t) acc[t] = (floatx4){0.f, 0.f, 0.f, 0.f};

#pragma unroll
  for (int s = 0; s < NS; ++s) {
#pragma unroll
    for (int t = 0; t < 4; ++t) {
      half8 bfrag = *(const half8*)&Wl[(t * 16 + l15) * SP + s * 32 + quad * 8];
      acc[t] = __builtin_amdgcn_mfma_f32_16x16x32_f16(afrag[s], bfrag, acc[t], 0, 0, 0);
    }
  }

#pragma unroll
  for (int r = 0; r < 4; ++r) {
    long node = base + quad * 4 + r;
    if (node < n) {
      float dv = dinv[node];
#pragma unroll
      for (int t = 0; t < 4; ++t)
        out[node * 64 + t * 16 + l15] = __float2half(acc[t][r] * dv);
    }
  }
}

// ------- gather core for one 8-node group: 8 lanes/node, 8 fp16 feats/lane ---

template <typename EPI>
__device__ __forceinline__ void gather8_one(int grp, const __half* __restrict__ hs,
                                            const int* __restrict__ ell,
                                            const int* __restrict__ cnt,
                                            const float* __restrict__ dinv,
                                            int n, int lane, EPI epi) {
  const int l8 = lane & 7;
  const int node = grp * 8 + (lane >> 3);
  const bool alive = node < n;
  const int nd = alive ? node : 0;
  const int c = alive ? cnt[nd] : 0;
  const float di = alive ? dinv[nd] : 0.f;
  const int* row = &ell[(long)nd * ELL_CAP];

  int s0 = (l8 < c) ? row[l8] : n;
  int s1 = (8 + l8 < c) ? row[8 + l8] : n;
  int s2 = (16 + l8 < c) ? row[16 + l8] : n;

  int cm = c;
  cm = max(cm, __shfl_xor(cm, 8, 64));
  cm = max(cm, __shfl_xor(cm, 16, 64));
  cm = max(cm, __shfl_xor(cm, 32, 64));
  const int nph = (cm + 7) >> 3;

  float accf[8];
  {
    float4 v = alive ? *(const float4*)&hs[(long)nd * 64 + l8 * 8]
                     : make_float4(0.f, 0.f, 0.f, 0.f);
    const unsigned* up = (const unsigned*)&v;
#pragma unroll
    for (int t = 0; t < 4; ++t) {
      float2 f = __half22float2(u2h(up[t]));
      accf[2 * t] = f.x; accf[2 * t + 1] = f.y;
    }
  }

  auto phase = [&](int reg) {
    int ss[8];
#pragma unroll
    for (int u = 0; u < 8; ++u) ss[u] = __shfl(reg, u, 8);
    float4 vv[8];
#pragma unroll
    for (int u = 0; u < 8; ++u) vv[u] = *(const float4*)&hs[(long)ss[u] * 64 + l8 * 8];
#pragma unroll
    for (int u = 0; u < 8; ++u) {
      const unsigned* up = (const unsigned*)&vv[u];
#pragma unroll
      for (int t = 0; t < 4; ++t) {
        float2 f = __half22float2(u2h(up[t]));
        accf[2 * t] += f.x; accf[2 * t + 1] += f.y;
      }
    }
  };

  if (nph > 0) phase(s0);
  if (nph > 1) phase(s1);
  if (nph > 2) phase(s2);
  for (int ph = 3; ph < nph; ++ph) {
    int reg = (ph * 8 + l8 < c) ? row[ph * 8 + l8] : n;
    phase(reg);
  }

  epi(accf, di, nd, l8, alive);
}

// ------- FUSED: gather0 (agg0 to LDS) + layer-1 MFMA GEMM --------------------

__global__ __launch_bounds__(256) void k_gather_gemm(const __half* __restrict__ hs0,
                                                     const int* __restrict__ ell,
                                                     const int* __restrict__ cnt,
                                                     const float* __restrict__ dinv,
                                                     const float* __restrict__ b0,
                                                     const float* __restrict__ W1,
                                                     __half* __restrict__ hs1, int n) {
  constexpr int SP = 72;
  __shared__ __half Wl[64 * SP];
  __shared__ __half As[64 * SP];
  const int tx = threadIdx.x;
  const int lane = tx & 63;
  const int w = tx >> 6;
  const long blockBase = (long)blockIdx.x * 64;

  for (int idx = tx; idx < 32 * 64; idx += 256) {
    int k2 = idx >> 6, col = idx & 63;
    __half2 h = __floats2half2_rn(W1[(2 * k2) * 64 + col], W1[(2 * k2 + 1) * 64 + col]);
    *(__half2*)&Wl[col * SP + 2 * k2] = h;
  }

#pragma unroll
  for (int p = 0; p < 2; ++p) {
    int g = blockIdx.x * 8 + w * 2 + p;
    gather8_one(g, hs0, ell, cnt, dinv, n, lane,
                [&](const float (&accf)[8], float di, int nd, int l8, bool alive) {
      if (!alive) return;
      int row = (int)(nd - blockBase);
      float4 bv0 = *(const float4*)&b0[l8 * 8];
      float4 bv1 = *(const float4*)&b0[l8 * 8 + 4];
      uint4 o;
      o.x = h2u(__floats2half2_rn(fmaxf(bv0.x + di * accf[0], 0.f),
                                  fmaxf(bv0.y + di * accf[1], 0.f)));
      o.y = h2u(__floats2half2_rn(fmaxf(bv0.z + di * accf[2], 0.f),
                                  fmaxf(bv0.w + di * accf[3], 0.f)));
      o.z = h2u(__floats2half2_rn(fmaxf(bv1.x + di * accf[4], 0.f),
                                  fmaxf(bv1.y + di * accf[5], 0.f)));
      o.w = h2u(__floats2half2_rn(fmaxf(bv1.z + di * accf[6], 0.f),
                                  fmaxf(bv1.w + di * accf[7], 0.f)));
      *(uint4*)&As[row * SP + l8 * 8] = o;
    });
  }
  __syncthreads();

  const int l15 = lane & 15;
  const int quad = lane >> 4;
  half8 afrag[2];
#pragma unroll
  for (int s = 0; s < 2; ++s)
    afrag[s] = *(const half8*)&As[(w * 16 + l15) * SP + s * 32 + quad * 8];

  floatx4 acc[4];
#pragma unroll
  for (int t = 0; t < 4; ++t) acc[t] = (floatx4){0.f, 0.f, 0.f, 0.f};
#pragma unroll
  for (int s = 0; s < 2; ++s) {
#pragma unroll
    for (int t = 0; t < 4; ++t) {
      half8 bfrag = *(const half8*)&Wl[(t * 16 + l15) * SP + s * 32 + quad * 8];
      acc[t] = __builtin_amdgcn_mfma_f32_16x16x32_f16(afrag[s], bfrag, acc[t], 0, 0, 0);
    }
  }

#pragma unroll
  for (int r = 0; r < 4; ++r) {
    long node = blockBase + w * 16 + quad * 4 + r;
    if (node < n) {
      float dv = dinv[node];
#pragma unroll
      for (int t = 0; t < 4; ++t)
        hs1[node * 64 + t * 16 + l15] = __float2half(acc[t][r] * dv);
    }
  }
}

// h2s[node] = dinv[node] * ( relu(b1 + di*acc) . W2 )   (pre-scaled for layer 2)
__global__ __launch_bounds__(256) void k_gather64x8_dot(const __half* __restrict__ hs,
                                                        const int* __restrict__ ell,
                                                        const int* __restrict__ cnt,
                                                        const float* __restrict__ dinv,
                                                        const float* __restrict__ b1,
                                                        const float* __restrict__ W2,
                                                        float* __restrict__ h2s, int n) {
  if (blockIdx.x == 0 && threadIdx.x == 0) h2s[n] = 0.f;
  const int wave = (blockIdx.x * 256 + threadIdx.x) >> 6;
  gather8_one(wave, hs, ell, cnt, dinv, n, threadIdx.x & 63,
              [&](const float (&accf)[8], float di, int node, int l8, bool alive) {
    float4 bv0 = *(const float4*)&b1[l8 * 8];
    float4 bv1 = *(const float4*)&b1[l8 * 8 + 4];
    float4 wv0 = *(const float4*)&W2[l8 * 8];
    float4 wv1 = *(const float4*)&W2[l8 * 8 + 4];
    float part = fmaxf(bv0.x + di * accf[0], 0.f) * wv0.x;
    part = fmaf(fmaxf(bv0.y + di * accf[1], 0.f), wv0.y, part);
    part = fmaf(fmaxf(bv0.z + di * accf[2], 0.f), wv0.z, part);
    part = fmaf(fmaxf(bv0.w + di * accf[3], 0.f), wv0.w, part);
    part = fmaf(fmaxf(bv1.x + di * accf[4], 0.f), wv1.x, part);
    part = fmaf(fmaxf(bv1.y + di * accf[5], 0.f), wv1.y, part);
    part = fmaf(fmaxf(bv1.z + di * accf[6], 0.f), wv1.z, part);
    part = fmaf(fmaxf(bv1.w + di * accf[7], 0.f), wv1.w, part);
#pragma unroll
    for (int off = 1; off < 8; off <<= 1) part += __shfl_xor(part, off, 8);
    if (alive && l8 == 0) h2s[node] = di * part;
  });
}

// ---- dim-1 gather + MLP head fused, x8 ----

__global__ __launch_bounds__(256) void k_gather1_mlp_x8(const float* __restrict__ h2s,
                                                        const int* __restrict__ ell,
                                                        const int* __restrict__ cnt,
                                                        const float* __restrict__ dinv,
                                                        const float* __restrict__ b2,
                                                        const float* __restrict__ Wm1,
                                                        const float* __restrict__ bm1,
                                                        const float* __restrict__ Wm2,
                                                        const float* __restrict__ bm2,
                                                        float* __restrict__ out, int n) {
  __shared__ float w1s[64], w2s[64], b1s[64];
  if (threadIdx.x < 64) {
    w1s[threadIdx.x] = Wm1[threadIdx.x];
    w2s[threadIdx.x] = Wm2[threadIdx.x];
    b1s[threadIdx.x] = bm1[threadIdx.x];
  }
  __syncthreads();
  const int tid = threadIdx.x;
  const int lane = tid & 63;
  const int l8 = lane & 7;
  const int wave = (blockIdx.x * 256 + tid) >> 6;
  const int node = wave * 8 + (lane >> 3);
  const bool alive = node < n;
  const int nd = alive ? node : 0;
  const int c = alive ? cnt[nd] : 0;
  const float di = alive ? dinv[nd] : 0.f;
  const int* row = &ell[(long)nd * ELL_CAP];

  int cm = c;
  cm = max(cm, __shfl_xor(cm, 8, 64));
  cm = max(cm, __shfl_xor(cm, 16, 64));
  cm = max(cm, __shfl_xor(cm, 32, 64));
  const int nph = (cm + 7) >> 3;

  float acc = (alive && l8 == 0) ? h2s[nd] : 0.f;
  for (int ph = 0; ph < nph; ++ph) {
    int j = ph * 8 + l8;
    int s = (j < c) ? row[j] : n;
    acc += h2s[s];
  }
#pragma unroll
  for (int off = 1; off < 8; off <<= 1) acc += __shfl_xor(acc, off, 8);

  const float sv = b2[0] + di * acc;
  float o = 0.f;
#pragma unroll
  for (int q = 0; q < 8; ++q) {
    int j = l8 * 8 + q;
    o = fmaf(fmaxf(fmaf(sv, w1s[j], b1s[j]), 0.f), w2s[j], o);
  }
#pragma unroll
  for (int off = 1; off < 8; off <<= 1) o += __shfl_xor(o, off, 8);
  if (alive && l8 == 0) out[nd] = o + bm2[0];
}

// ---------------- launch ----------------
// LEDGER-COMPLETION ROUND: every kernel launched TWICE (all are idempotent —
// deterministic pure functions of inputs they do not modify). With baseline
// 199.9us:  dur - 199.9 = sum(T_kernel) + 6*OH  and  fixed = 199.9 - (dur-199.9).
// Combined with R3 (gathers+2OH = 50.4), this fully decomposes the runtime.
// Cooperative mega-kernel path permanently abandoned (R4-R6: silent no-op,
// then GPU hang killing the container).

extern "C" void kernel_launch(void* const* d_in, const int* in_sizes, int n_in,
                              void* d_out, int out_size, void* d_ws, size_t ws_size,
                              hipStream_t stream) {
  const float* x   = (const float*)d_in[0];
  const int*   ei  = (const int*)d_in[1];
  const float* W0  = (const float*)d_in[2];
  const float* b0  = (const float*)d_in[3];
  const float* W1  = (const float*)d_in[4];
  const float* b1  = (const float*)d_in[5];
  const float* W2  = (const float*)d_in[6];
  const float* b2  = (const float*)d_in[7];
  const float* Wm1 = (const float*)d_in[8];
  const float* bm1 = (const float*)d_in[9];
  const float* Wm2 = (const float*)d_in[10];
  const float* bm2 = (const float*)d_in[11];

  const int n = in_sizes[0] / 128;  // 100000
  const int E = in_sizes[1] / 2;    // 1200000
  const int* src = ei;
  const int* dst = ei + E;

  float*  ws   = (float*)d_ws;
  float*  dinv = ws;                                   // n floats
  int*    cnt  = (int*)(ws + n);                       // n ints
  int*    ell  = cnt + n;                              // 48n ints
  __half* bufA = (__half*)(ell + (size_t)n * ELL_CAP); // (n+1)*64 halves (hs0)
  __half* bufB = bufA + (size_t)(n + 1) * 64;          // (n+1)*64 halves (hs1)
  float*  h2s  = (float*)(bufB + (size_t)(n + 1) * 64);// n+1 floats
  int*    hist_g = (int*)(h2s + (n + 1));              // NBUCK*SLB ints
  int*    buckets = (int*)bufA;                        // alias; dead before GEMM0
                                                       // (safe across kernel bounds)

  const int g8b = (((n + 7) / 8) + 3) / 4;
  const int mfb = (n + 63) / 64;

  k_bucket<<<SLB, 1024, 0, stream>>>(src, dst, hist_g, buckets, E);
  k_bucket<<<SLB, 1024, 0, stream>>>(src, dst, hist_g, buckets, E);

  k_ellbuild<<<NBUCK, 512, 0, stream>>>(buckets, hist_g, cnt, ell, dinv, n);
  k_ellbuild<<<NBUCK, 512, 0, stream>>>(buckets, hist_g, cnt, ell, dinv, n);

  k_gemm_mfma128<<<mfb, 256, 0, stream>>>(x, W0, dinv, bufA,
                                          bufA + (size_t)n * 64,
                                          bufB + (size_t)n * 64, n);
  k_gemm_mfma128<<<mfb, 256, 0, stream>>>(x, W0, dinv, bufA,
                                          bufA + (size_t)n * 64,
                                          bufB + (size_t)n * 64, n);

  k_gather_gemm<<<mfb, 256, 0, stream>>>(bufA, ell, cnt, dinv, b0, W1, bufB, n);
  k_gather_gemm<<<mfb, 256, 0, stream>>>(bufA, ell, cnt, dinv, b0, W1, bufB, n);

  k_gather64x8_dot<<<g8b, 256, 0, stream>>>(bufB, ell, cnt, dinv, b1, W2, h2s, n);
  k_gather64x8_dot<<<g8b, 256, 0, stream>>>(bufB, ell, cnt, dinv, b1, W2, h2s, n);

  k_gather1_mlp_x8<<<g8b, 256, 0, stream>>>(h2s, ell, cnt, dinv, b2, Wm1, bm1,
                                            Wm2, bm2, (float*)d_out, n);
  k_gather1_mlp_x8<<<g8b, 256, 0, stream>>>(h2s, ell, cnt, dinv, b2, Wm1, bm1,
                                            Wm2, bm2, (float*)d_out, n);
}

// Round 8
// 259.964 us; speedup vs baseline: 1.1197x; 1.1197x over previous
//
#include <hip/hip_runtime.h>
#include <hip/hip_fp16.h>
#include <math.h>

#define ELL_CAP 48

typedef _Float16 half8 __attribute__((ext_vector_type(8)));
typedef float floatx4 __attribute__((ext_vector_type(4)));

// ---------------- small helpers ----------------

__device__ __forceinline__ __half2 u2h(unsigned u) {
  __half2 h; __builtin_memcpy(&h, &u, 4); return h;
}
__device__ __forceinline__ unsigned h2u(__half2 h) {
  unsigned u; __builtin_memcpy(&u, &h, 4); return u;
}

// ------ P-1: zero the degree counters (needed before atomic scatter) --------

__global__ __launch_bounds__(1024) void k_zero(int* __restrict__ cnt, int n) {
  int i = blockIdx.x * 1024 + threadIdx.x;
  if (i < n) cnt[i] = 0;
}

// ------ P0: direct ELL build, single pass, global atomics -------------------
// Replaces the two-pass bucket+ellbuild (22us, 40MB bucket round-trip) with
// one pass: coalesced edge reads, 1.2M atomics (avg 12-way), 1.2M scattered
// 4B stores (fire-and-forget). Row order = atomic arrival order (sum is
// order-independent up to fp16-accum ulps). cnt holds the RAW in-degree;
// consumers cap at ELL_CAP; dinv uses raw (matches reference exactly).

__global__ __launch_bounds__(1024) void k_scatter(const int* __restrict__ src,
                                                  const int* __restrict__ dst,
                                                  int* __restrict__ cnt,
                                                  int* __restrict__ ell, int E) {
  int i = blockIdx.x * 1024 + threadIdx.x;
  if (i < E) {
    int s = src[i], d = dst[i];
    int pos = atomicAdd(&cnt[d], 1);
    if (pos < ELL_CAP) ell[(long)d * ELL_CAP + pos] = s;
  }
}

// ---------------- MFMA GEMM (layer 0): hs0 = dinv * (x @ W0), fp16 ----------
// Epilogue also computes+stores dinv from raw cnt (scatter has finished), and
// zeroes the dead-slot rows of bufA/bufB.

__global__ __launch_bounds__(256) void k_gemm_mfma128(const float* __restrict__ Xf,
                                                      const float* __restrict__ W,
                                                      const int* __restrict__ cnt,
                                                      float* __restrict__ dinv,
                                                      __half* __restrict__ out,
                                                      __half* __restrict__ zrowA,
                                                      __half* __restrict__ zrowB, int n) {
  constexpr int K = 128, SP = K + 8, NS = K / 32;
  __shared__ __half Wl[64 * SP];
  const int tx = threadIdx.x;

  if (blockIdx.x == 0 && tx < 64) { zrowA[tx] = __float2half(0.f); zrowB[tx] = __float2half(0.f); }

  for (int idx = tx; idx < (K / 2) * 64; idx += 256) {
    int k2 = idx >> 6, col = idx & 63;
    __half2 h = __floats2half2_rn(W[(2 * k2) * 64 + col], W[(2 * k2 + 1) * 64 + col]);
    *(__half2*)&Wl[col * SP + 2 * k2] = h;
  }
  __syncthreads();

  const int lane = tx & 63;
  const int l15 = lane & 15;
  const int quad = lane >> 4;
  const long base = (long)blockIdx.x * 64 + (tx >> 6) * 16;

  long arow = base + l15;
  if (arow >= n) arow = n - 1;  // clamp; stores predicated

  half8 afrag[NS];
#pragma unroll
  for (int s = 0; s < NS; ++s) {
    float4 lo = *(const float4*)&Xf[arow * K + s * 32 + quad * 8];
    float4 hi = *(const float4*)&Xf[arow * K + s * 32 + quad * 8 + 4];
    half8 a;
    a[0] = (_Float16)lo.x; a[1] = (_Float16)lo.y;
    a[2] = (_Float16)lo.z; a[3] = (_Float16)lo.w;
    a[4] = (_Float16)hi.x; a[5] = (_Float16)hi.y;
    a[6] = (_Float16)hi.z; a[7] = (_Float16)hi.w;
    afrag[s] = a;
  }

  floatx4 acc[4];
#pragma unroll
  for (int t = 0; t < 4; ++t) acc[t] = (floatx4){0.f, 0.f, 0.f, 0.f};

#pragma unroll
  for (int s = 0; s < NS; ++s) {
#pragma unroll
    for (int t = 0; t < 4; ++t) {
      half8 bfrag = *(const half8*)&Wl[(t * 16 + l15) * SP + s * 32 + quad * 8];
      acc[t] = __builtin_amdgcn_mfma_f32_16x16x32_f16(afrag[s], bfrag, acc[t], 0, 0, 0);
    }
  }

#pragma unroll
  for (int r = 0; r < 4; ++r) {
    long node = base + quad * 4 + r;
    if (node < n) {
      float dv = 1.0f / sqrtf((float)(cnt[node] + 1));  // raw deg +1 self-loop
      if (l15 == 0) dinv[node] = dv;                    // one writer per node
#pragma unroll
      for (int t = 0; t < 4; ++t)
        out[node * 64 + t * 16 + l15] = __float2half(acc[t][r] * dv);
    }
  }
}

// ------- gather core for one 8-node group: 8 lanes/node, 8 fp16 feats/lane ---

template <typename EPI>
__device__ __forceinline__ void gather8_one(int grp, const __half* __restrict__ hs,
                                            const int* __restrict__ ell,
                                            const int* __restrict__ cnt,
                                            const float* __restrict__ dinv,
                                            int n, int lane, EPI epi) {
  const int l8 = lane & 7;
  const int node = grp * 8 + (lane >> 3);
  const bool alive = node < n;
  const int nd = alive ? node : 0;
  const int c = alive ? min(cnt[nd], ELL_CAP) : 0;   // cnt is raw; cap here
  const float di = alive ? dinv[nd] : 0.f;
  const int* row = &ell[(long)nd * ELL_CAP];

  int s0 = (l8 < c) ? row[l8] : n;
  int s1 = (8 + l8 < c) ? row[8 + l8] : n;
  int s2 = (16 + l8 < c) ? row[16 + l8] : n;

  int cm = c;
  cm = max(cm, __shfl_xor(cm, 8, 64));
  cm = max(cm, __shfl_xor(cm, 16, 64));
  cm = max(cm, __shfl_xor(cm, 32, 64));
  const int nph = (cm + 7) >> 3;

  float accf[8];
  {
    float4 v = alive ? *(const float4*)&hs[(long)nd * 64 + l8 * 8]
                     : make_float4(0.f, 0.f, 0.f, 0.f);
    const unsigned* up = (const unsigned*)&v;
#pragma unroll
    for (int t = 0; t < 4; ++t) {
      float2 f = __half22float2(u2h(up[t]));
      accf[2 * t] = f.x; accf[2 * t + 1] = f.y;
    }
  }

  auto phase = [&](int reg) {
    int ss[8];
#pragma unroll
    for (int u = 0; u < 8; ++u) ss[u] = __shfl(reg, u, 8);
    float4 vv[8];
#pragma unroll
    for (int u = 0; u < 8; ++u) vv[u] = *(const float4*)&hs[(long)ss[u] * 64 + l8 * 8];
#pragma unroll
    for (int u = 0; u < 8; ++u) {
      const unsigned* up = (const unsigned*)&vv[u];
#pragma unroll
      for (int t = 0; t < 4; ++t) {
        float2 f = __half22float2(u2h(up[t]));
        accf[2 * t] += f.x; accf[2 * t + 1] += f.y;
      }
    }
  };

  if (nph > 0) phase(s0);
  if (nph > 1) phase(s1);
  if (nph > 2) phase(s2);
  for (int ph = 3; ph < nph; ++ph) {
    int reg = (ph * 8 + l8 < c) ? row[ph * 8 + l8] : n;
    phase(reg);
  }

  epi(accf, di, nd, l8, alive);
}

// ------- FUSED: gather0 (agg0 to LDS) + layer-1 MFMA GEMM --------------------

__global__ __launch_bounds__(256) void k_gather_gemm(const __half* __restrict__ hs0,
                                                     const int* __restrict__ ell,
                                                     const int* __restrict__ cnt,
                                                     const float* __restrict__ dinv,
                                                     const float* __restrict__ b0,
                                                     const float* __restrict__ W1,
                                                     __half* __restrict__ hs1, int n) {
  constexpr int SP = 72;
  __shared__ __half Wl[64 * SP];
  __shared__ __half As[64 * SP];
  const int tx = threadIdx.x;
  const int lane = tx & 63;
  const int w = tx >> 6;
  const long blockBase = (long)blockIdx.x * 64;

  for (int idx = tx; idx < 32 * 64; idx += 256) {
    int k2 = idx >> 6, col = idx & 63;
    __half2 h = __floats2half2_rn(W1[(2 * k2) * 64 + col], W1[(2 * k2 + 1) * 64 + col]);
    *(__half2*)&Wl[col * SP + 2 * k2] = h;
  }

#pragma unroll
  for (int p = 0; p < 2; ++p) {
    int g = blockIdx.x * 8 + w * 2 + p;
    gather8_one(g, hs0, ell, cnt, dinv, n, lane,
                [&](const float (&accf)[8], float di, int nd, int l8, bool alive) {
      if (!alive) return;
      int row = (int)(nd - blockBase);
      float4 bv0 = *(const float4*)&b0[l8 * 8];
      float4 bv1 = *(const float4*)&b0[l8 * 8 + 4];
      uint4 o;
      o.x = h2u(__floats2half2_rn(fmaxf(bv0.x + di * accf[0], 0.f),
                                  fmaxf(bv0.y + di * accf[1], 0.f)));
      o.y = h2u(__floats2half2_rn(fmaxf(bv0.z + di * accf[2], 0.f),
                                  fmaxf(bv0.w + di * accf[3], 0.f)));
      o.z = h2u(__floats2half2_rn(fmaxf(bv1.x + di * accf[4], 0.f),
                                  fmaxf(bv1.y + di * accf[5], 0.f)));
      o.w = h2u(__floats2half2_rn(fmaxf(bv1.z + di * accf[6], 0.f),
                                  fmaxf(bv1.w + di * accf[7], 0.f)));
      *(uint4*)&As[row * SP + l8 * 8] = o;
    });
  }
  __syncthreads();

  const int l15 = lane & 15;
  const int quad = lane >> 4;
  half8 afrag[2];
#pragma unroll
  for (int s = 0; s < 2; ++s)
    afrag[s] = *(const half8*)&As[(w * 16 + l15) * SP + s * 32 + quad * 8];

  floatx4 acc[4];
#pragma unroll
  for (int t = 0; t < 4; ++t) acc[t] = (floatx4){0.f, 0.f, 0.f, 0.f};
#pragma unroll
  for (int s = 0; s < 2; ++s) {
#pragma unroll
    for (int t = 0; t < 4; ++t) {
      half8 bfrag = *(const half8*)&Wl[(t * 16 + l15) * SP + s * 32 + quad * 8];
      acc[t] = __builtin_amdgcn_mfma_f32_16x16x32_f16(afrag[s], bfrag, acc[t], 0, 0, 0);
    }
  }

#pragma unroll
  for (int r = 0; r < 4; ++r) {
    long node = blockBase + w * 16 + quad * 4 + r;
    if (node < n) {
      float dv = dinv[node];
#pragma unroll
      for (int t = 0; t < 4; ++t)
        hs1[node * 64 + t * 16 + l15] = __float2half(acc[t][r] * dv);
    }
  }
}

// h2s[node] = dinv[node] * ( relu(b1 + di*acc) . W2 )   (pre-scaled for layer 2)
__global__ __launch_bounds__(256) void k_gather64x8_dot(const __half* __restrict__ hs,
                                                        const int* __restrict__ ell,
                                                        const int* __restrict__ cnt,
                                                        const float* __restrict__ dinv,
                                                        const float* __restrict__ b1,
                                                        const float* __restrict__ W2,
                                                        float* __restrict__ h2s, int n) {
  if (blockIdx.x == 0 && threadIdx.x == 0) h2s[n] = 0.f;
  const int wave = (blockIdx.x * 256 + threadIdx.x) >> 6;
  gather8_one(wave, hs, ell, cnt, dinv, n, threadIdx.x & 63,
              [&](const float (&accf)[8], float di, int node, int l8, bool alive) {
    float4 bv0 = *(const float4*)&b1[l8 * 8];
    float4 bv1 = *(const float4*)&b1[l8 * 8 + 4];
    float4 wv0 = *(const float4*)&W2[l8 * 8];
    float4 wv1 = *(const float4*)&W2[l8 * 8 + 4];
    float part = fmaxf(bv0.x + di * accf[0], 0.f) * wv0.x;
    part = fmaf(fmaxf(bv0.y + di * accf[1], 0.f), wv0.y, part);
    part = fmaf(fmaxf(bv0.z + di * accf[2], 0.f), wv0.z, part);
    part = fmaf(fmaxf(bv0.w + di * accf[3], 0.f), wv0.w, part);
    part = fmaf(fmaxf(bv1.x + di * accf[4], 0.f), wv1.x, part);
    part = fmaf(fmaxf(bv1.y + di * accf[5], 0.f), wv1.y, part);
    part = fmaf(fmaxf(bv1.z + di * accf[6], 0.f), wv1.z, part);
    part = fmaf(fmaxf(bv1.w + di * accf[7], 0.f), wv1.w, part);
#pragma unroll
    for (int off = 1; off < 8; off <<= 1) part += __shfl_xor(part, off, 8);
    if (alive && l8 == 0) h2s[node] = di * part;
  });
}

// ---- dim-1 gather + MLP head fused, x8 ----

__global__ __launch_bounds__(256) void k_gather1_mlp_x8(const float* __restrict__ h2s,
                                                        const int* __restrict__ ell,
                                                        const int* __restrict__ cnt,
                                                        const float* __restrict__ dinv,
                                                        const float* __restrict__ b2,
                                                        const float* __restrict__ Wm1,
                                                        const float* __restrict__ bm1,
                                                        const float* __restrict__ Wm2,
                                                        const float* __restrict__ bm2,
                                                        float* __restrict__ out, int n) {
  __shared__ float w1s[64], w2s[64], b1s[64];
  if (threadIdx.x < 64) {
    w1s[threadIdx.x] = Wm1[threadIdx.x];
    w2s[threadIdx.x] = Wm2[threadIdx.x];
    b1s[threadIdx.x] = bm1[threadIdx.x];
  }
  __syncthreads();
  const int tid = threadIdx.x;
  const int lane = tid & 63;
  const int l8 = lane & 7;
  const int wave = (blockIdx.x * 256 + tid) >> 6;
  const int node = wave * 8 + (lane >> 3);
  const bool alive = node < n;
  const int nd = alive ? node : 0;
  const int c = alive ? min(cnt[nd], ELL_CAP) : 0;  // cnt raw; cap
  const float di = alive ? dinv[nd] : 0.f;
  const int* row = &ell[(long)nd * ELL_CAP];

  int cm = c;
  cm = max(cm, __shfl_xor(cm, 8, 64));
  cm = max(cm, __shfl_xor(cm, 16, 64));
  cm = max(cm, __shfl_xor(cm, 32, 64));
  const int nph = (cm + 7) >> 3;

  float acc = (alive && l8 == 0) ? h2s[nd] : 0.f;
  for (int ph = 0; ph < nph; ++ph) {
    int j = ph * 8 + l8;
    int s = (j < c) ? row[j] : n;
    acc += h2s[s];
  }
#pragma unroll
  for (int off = 1; off < 8; off <<= 1) acc += __shfl_xor(acc, off, 8);

  const float sv = b2[0] + di * acc;
  float o = 0.f;
#pragma unroll
  for (int q = 0; q < 8; ++q) {
    int j = l8 * 8 + q;
    o = fmaf(fmaxf(fmaf(sv, w1s[j], b1s[j]), 0.f), w2s[j], o);
  }
#pragma unroll
  for (int off = 1; off < 8; off <<= 1) o += __shfl_xor(o, off, 8);
  if (alive && l8 == 0) out[nd] = o + bm2[0];
}

// ---------------- launch ----------------
// R8: preprocessing rewritten as zero+direct-atomic-scatter (was two-pass
// bucket+ellbuild, ~22us marginal per R7 ledger; direct build ~7us incl. the
// extra tiny launch). Everything downstream unchanged. Ledger (R3+R7):
// gathers+2OH=50.4, non-gathers+4OH=40.8, harness-fixed ~109 (untouchable).

extern "C" void kernel_launch(void* const* d_in, const int* in_sizes, int n_in,
                              void* d_out, int out_size, void* d_ws, size_t ws_size,
                              hipStream_t stream) {
  const float* x   = (const float*)d_in[0];
  const int*   ei  = (const int*)d_in[1];
  const float* W0  = (const float*)d_in[2];
  const float* b0  = (const float*)d_in[3];
  const float* W1  = (const float*)d_in[4];
  const float* b1  = (const float*)d_in[5];
  const float* W2  = (const float*)d_in[6];
  const float* b2  = (const float*)d_in[7];
  const float* Wm1 = (const float*)d_in[8];
  const float* bm1 = (const float*)d_in[9];
  const float* Wm2 = (const float*)d_in[10];
  const float* bm2 = (const float*)d_in[11];

  const int n = in_sizes[0] / 128;  // 100000
  const int E = in_sizes[1] / 2;    // 1200000
  const int* src = ei;
  const int* dst = ei + E;

  float*  ws   = (float*)d_ws;
  float*  dinv = ws;                                   // n floats
  int*    cnt  = (int*)(ws + n);                       // n ints
  int*    ell  = cnt + n;                              // 48n ints
  __half* bufA = (__half*)(ell + (size_t)n * ELL_CAP); // (n+1)*64 halves (hs0)
  __half* bufB = bufA + (size_t)(n + 1) * 64;          // (n+1)*64 halves (hs1)
  float*  h2s  = (float*)(bufB + (size_t)(n + 1) * 64);// n+1 floats

  const int g8b = (((n + 7) / 8) + 3) / 4;
  const int mfb = (n + 63) / 64;

  k_zero<<<(n + 1023) / 1024, 1024, 0, stream>>>(cnt, n);
  k_scatter<<<(E + 1023) / 1024, 1024, 0, stream>>>(src, dst, cnt, ell, E);

  // layer 0: hs0 = dinv*(x @ W0) -> bufA; computes+stores dinv; zeroes dead rows
  k_gemm_mfma128<<<mfb, 256, 0, stream>>>(x, W0, cnt, dinv, bufA,
                                          bufA + (size_t)n * 64,
                                          bufB + (size_t)n * 64, n);

  k_gather_gemm<<<mfb, 256, 0, stream>>>(bufA, ell, cnt, dinv, b0, W1, bufB, n);

  k_gather64x8_dot<<<g8b, 256, 0, stream>>>(bufB, ell, cnt, dinv, b1, W2, h2s, n);

  k_gather1_mlp_x8<<<g8b, 256, 0, stream>>>(h2s, ell, cnt, dinv, b2, Wm1, bm1,
                                            Wm2, bm2, (float*)d_out, n);
}

// Round 9
// 199.444 us; speedup vs baseline: 1.4595x; 1.3034x over previous
//
#include <hip/hip_runtime.h>
#include <hip/hip_fp16.h>
#include <math.h>

#define ELL_CAP 48
#define NBUCK 391   // ceil(100000/256)
#define SLB 256     // bucket-writer blocks
#define SLICE 48    // per-(block,bucket) slice capacity (mean 12, P(>=48)~3e-15)

typedef _Float16 half8 __attribute__((ext_vector_type(8)));
typedef float floatx4 __attribute__((ext_vector_type(4)));

// ---------------- small helpers ----------------

__device__ __forceinline__ __half2 u2h(unsigned u) {
  __half2 h; __builtin_memcpy(&h, &u, 4); return h;
}
__device__ __forceinline__ unsigned h2u(__half2 h) {
  unsigned u; __builtin_memcpy(&u, &h, 4); return u;
}

// ------ Phase A: slice-partitioned bucket scatter, SINGLE sweep --------------
// R9 fixes vs R1:
//  * hist_g layout TRANSPOSED to [block][bucket]: each block writes ~25
//    contiguous block-exclusive lines instead of 391 stride-256 sub-line RMWs
//    (R8's k_scatter counters proved cross-XCD sub-line writes are the poison:
//    WRITE_SIZE showed 64B writeback per 4B store).
//  * edge loads vectorized int4 x 4 edges/thread; slice bounds 16-edge-aligned
//    so the 16B loads are aligned.

__global__ __launch_bounds__(1024) void k_bucket(const int* __restrict__ src,
                                                 const int* __restrict__ dst,
                                                 int* __restrict__ hist_g,
                                                 int* __restrict__ buckets, int E) {
  __shared__ int histL[NBUCK];
  const int tid = threadIdx.x, b = blockIdx.x;
  for (int i = tid; i < NBUCK; i += 1024) histL[i] = 0;
  __syncthreads();

  const long e16 = E >> 4;  // E/16 = 75000
  const long s0 = 16 * ((long)b * e16 / SLB);
  const long s1 = (b == SLB - 1) ? E : 16 * ((long)(b + 1) * e16 / SLB);

  for (long e = s0 + (long)tid * 4; e < s1; e += 4096) {
    if (e + 4 <= s1) {
      int4 sv = *(const int4*)&src[e];   // aligned: e % 4 == 0
      int4 dv = *(const int4*)&dst[e];
      int ss[4] = {sv.x, sv.y, sv.z, sv.w};
      int dd[4] = {dv.x, dv.y, dv.z, dv.w};
#pragma unroll
      for (int k = 0; k < 4; ++k) {
        int bi = dd[k] >> 8;
        int pos = atomicAdd(&histL[bi], 1);
        if (pos < SLICE)
          buckets[(long)bi * (SLB * SLICE) + b * SLICE + pos] =
              ((dd[k] & 255) << 24) | ss[k];
      }
    } else {
      for (long ee = e; ee < s1; ++ee) {
        int s = src[ee], d = dst[ee];
        int bi = d >> 8;
        int pos = atomicAdd(&histL[bi], 1);
        if (pos < SLICE)
          buckets[(long)bi * (SLB * SLICE) + b * SLICE + pos] = ((d & 255) << 24) | s;
      }
    }
  }
  __syncthreads();

  // coalesced, block-exclusive: hist_g[b][i]
  for (int i = tid; i < NBUCK; i += 1024) hist_g[b * NBUCK + i] = min(histL[i], SLICE);
}

// ------- Phase B: per-bucket ELL build in LDS from 256 slices (int4 reads) ---

__global__ __launch_bounds__(512) void k_ellbuild(const int* __restrict__ buckets,
                                                  const int* __restrict__ hist_g,
                                                  int* __restrict__ cnt,
                                                  int* __restrict__ ell,
                                                  float* __restrict__ dinv, int n) {
  __shared__ int cnt_l[256];
  __shared__ int ell_l[256 * ELL_CAP];
  __shared__ int cslice[SLB];
  __shared__ unsigned char lim4[256];
  const int b = blockIdx.x, tid = threadIdx.x;
  if (tid < 256) cnt_l[tid] = 0;
  // transposed hist read: strided gather, read-only (cached; no RMW ping-pong)
  if (tid < SLB) cslice[tid] = hist_g[tid * NBUCK + b];
  __syncthreads();

  const int s = tid >> 1;
  const int m = cslice[s];
  const int4* bk4 = (const int4*)(buckets + (long)b * (SLB * SLICE) + s * SLICE);
  const int nq = (m + 3) >> 2;
  for (int j = (tid & 1); j < nq; j += 2) {
    int4 q = bk4[j];
    const int e0 = j * 4;
    int v[4] = {q.x, q.y, q.z, q.w};
#pragma unroll
    for (int k = 0; k < 4; ++k) {
      if (e0 + k < m) {
        int p = v[k];
        int ld = ((unsigned)p) >> 24;
        int pos = atomicAdd(&cnt_l[ld], 1);
        if (pos < ELL_CAP) ell_l[ld * ELL_CAP + pos] = p & 0xFFFFFF;
      }
    }
  }
  __syncthreads();

  const int d0 = b << 8;
  const int node = d0 + tid;
  const int rows = min(256, n - d0);
  if (tid < rows) {
    int c = cnt_l[tid];
    if (c > ELL_CAP) c = ELL_CAP;
    cnt[node] = c;
    dinv[node] = 1.0f / sqrtf((float)(c + 1));  // +1 self-loop, precise
    lim4[tid] = (unsigned char)((c + 3) >> 2);
  }
  __syncthreads();

  int4* dst4 = (int4*)(ell + (long)d0 * ELL_CAP);
  const int4* src4 = (const int4*)ell_l;
  const int tot = rows * 12;
  for (int i = tid; i < tot; i += 512) {
    int r = i / 12, w = i - r * 12;
    if (w < (int)lim4[r]) dst4[i] = src4[i];
  }
}

// ---------------- MFMA GEMM (layer 0): hs0 = dinv * (x @ W0), fp16 ----------

__global__ __launch_bounds__(256) void k_gemm_mfma128(const float* __restrict__ Xf,
                                                      const float* __restrict__ W,
                                                      const float* __restrict__ dinv,
                                                      __half* __restrict__ out,
                                                      __half* __restrict__ zrowA,
                                                      __half* __restrict__ zrowB, int n) {
  constexpr int K = 128, SP = K + 8, NS = K / 32;
  __shared__ __half Wl[64 * SP];
  const int tx = threadIdx.x;

  if (blockIdx.x == 0 && tx < 64) { zrowA[tx] = __float2half(0.f); zrowB[tx] = __float2half(0.f); }

  for (int idx = tx; idx < (K / 2) * 64; idx += 256) {
    int k2 = idx >> 6, col = idx & 63;
    __half2 h = __floats2half2_rn(W[(2 * k2) * 64 + col], W[(2 * k2 + 1) * 64 + col]);
    *(__half2*)&Wl[col * SP + 2 * k2] = h;
  }
  __syncthreads();

  const int lane = tx & 63;
  const int l15 = lane & 15;
  const int quad = lane >> 4;
  const long base = (long)blockIdx.x * 64 + (tx >> 6) * 16;

  long arow = base + l15;
  if (arow >= n) arow = n - 1;  // clamp; stores predicated

  half8 afrag[NS];
#pragma unroll
  for (int s = 0; s < NS; ++s) {
    float4 lo = *(const float4*)&Xf[arow * K + s * 32 + quad * 8];
    float4 hi = *(const float4*)&Xf[arow * K + s * 32 + quad * 8 + 4];
    half8 a;
    a[0] = (_Float16)lo.x; a[1] = (_Float16)lo.y;
    a[2] = (_Float16)lo.z; a[3] = (_Float16)lo.w;
    a[4] = (_Float16)hi.x; a[5] = (_Float16)hi.y;
    a[6] = (_Float16)hi.z; a[7] = (_Float16)hi.w;
    afrag[s] = a;
  }

  floatx4 acc[4];
#pragma unroll
  for (int t = 0; t < 4; ++t) acc[t] = (floatx4){0.f, 0.f, 0.f, 0.f};

#pragma unroll
  for (int s = 0; s < NS; ++s) {
#pragma unroll
    for (int t = 0; t < 4; ++t) {
      half8 bfrag = *(const half8*)&Wl[(t * 16 + l15) * SP + s * 32 + quad * 8];
      acc[t] = __builtin_amdgcn_mfma_f32_16x16x32_f16(afrag[s], bfrag, acc[t], 0, 0, 0);
    }
  }

#pragma unroll
  for (int r = 0; r < 4; ++r) {
    long node = base + quad * 4 + r;
    if (node < n) {
      float dv = dinv[node];
#pragma unroll
      for (int t = 0; t < 4; ++t)
        out[node * 64 + t * 16 + l15] = __float2half(acc[t][r] * dv);
    }
  }
}

// ------- gather core for one 8-node group: 8 lanes/node, 8 fp16 feats/lane ---

template <typename EPI>
__device__ __forceinline__ void gather8_one(int grp, const __half* __restrict__ hs,
                                            const int* __restrict__ ell,
                                            const int* __restrict__ cnt,
                                            const float* __restrict__ dinv,
                                            int n, int lane, EPI epi) {
  const int l8 = lane & 7;
  const int node = grp * 8 + (lane >> 3);
  const bool alive = node < n;
  const int nd = alive ? node : 0;
  const int c = alive ? cnt[nd] : 0;
  const float di = alive ? dinv[nd] : 0.f;
  const int* row = &ell[(long)nd * ELL_CAP];

  int s0 = (l8 < c) ? row[l8] : n;
  int s1 = (8 + l8 < c) ? row[8 + l8] : n;
  int s2 = (16 + l8 < c) ? row[16 + l8] : n;

  int cm = c;
  cm = max(cm, __shfl_xor(cm, 8, 64));
  cm = max(cm, __shfl_xor(cm, 16, 64));
  cm = max(cm, __shfl_xor(cm, 32, 64));
  const int nph = (cm + 7) >> 3;

  float accf[8];
  {
    float4 v = alive ? *(const float4*)&hs[(long)nd * 64 + l8 * 8]
                     : make_float4(0.f, 0.f, 0.f, 0.f);
    const unsigned* up = (const unsigned*)&v;
#pragma unroll
    for (int t = 0; t < 4; ++t) {
      float2 f = __half22float2(u2h(up[t]));
      accf[2 * t] = f.x; accf[2 * t + 1] = f.y;
    }
  }

  auto phase = [&](int reg) {
    int ss[8];
#pragma unroll
    for (int u = 0; u < 8; ++u) ss[u] = __shfl(reg, u, 8);
    float4 vv[8];
#pragma unroll
    for (int u = 0; u < 8; ++u) vv[u] = *(const float4*)&hs[(long)ss[u] * 64 + l8 * 8];
#pragma unroll
    for (int u = 0; u < 8; ++u) {
      const unsigned* up = (const unsigned*)&vv[u];
#pragma unroll
      for (int t = 0; t < 4; ++t) {
        float2 f = __half22float2(u2h(up[t]));
        accf[2 * t] += f.x; accf[2 * t + 1] += f.y;
      }
    }
  };

  if (nph > 0) phase(s0);
  if (nph > 1) phase(s1);
  if (nph > 2) phase(s2);
  for (int ph = 3; ph < nph; ++ph) {
    int reg = (ph * 8 + l8 < c) ? row[ph * 8 + l8] : n;
    phase(reg);
  }

  epi(accf, di, nd, l8, alive);
}

// ------- FUSED: gather0 (agg0 to LDS) + layer-1 MFMA GEMM --------------------

__global__ __launch_bounds__(256) void k_gather_gemm(const __half* __restrict__ hs0,
                                                     const int* __restrict__ ell,
                                                     const int* __restrict__ cnt,
                                                     const float* __restrict__ dinv,
                                                     const float* __restrict__ b0,
                                                     const float* __restrict__ W1,
                                                     __half* __restrict__ hs1, int n) {
  constexpr int SP = 72;
  __shared__ __half Wl[64 * SP];
  __shared__ __half As[64 * SP];
  const int tx = threadIdx.x;
  const int lane = tx & 63;
  const int w = tx >> 6;
  const long blockBase = (long)blockIdx.x * 64;

  for (int idx = tx; idx < 32 * 64; idx += 256) {
    int k2 = idx >> 6, col = idx & 63;
    __half2 h = __floats2half2_rn(W1[(2 * k2) * 64 + col], W1[(2 * k2 + 1) * 64 + col]);
    *(__half2*)&Wl[col * SP + 2 * k2] = h;
  }

#pragma unroll
  for (int p = 0; p < 2; ++p) {
    int g = blockIdx.x * 8 + w * 2 + p;
    gather8_one(g, hs0, ell, cnt, dinv, n, lane,
                [&](const float (&accf)[8], float di, int nd, int l8, bool alive) {
      if (!alive) return;
      int row = (int)(nd - blockBase);
      float4 bv0 = *(const float4*)&b0[l8 * 8];
      float4 bv1 = *(const float4*)&b0[l8 * 8 + 4];
      uint4 o;
      o.x = h2u(__floats2half2_rn(fmaxf(bv0.x + di * accf[0], 0.f),
                                  fmaxf(bv0.y + di * accf[1], 0.f)));
      o.y = h2u(__floats2half2_rn(fmaxf(bv0.z + di * accf[2], 0.f),
                                  fmaxf(bv0.w + di * accf[3], 0.f)));
      o.z = h2u(__floats2half2_rn(fmaxf(bv1.x + di * accf[4], 0.f),
                                  fmaxf(bv1.y + di * accf[5], 0.f)));
      o.w = h2u(__floats2half2_rn(fmaxf(bv1.z + di * accf[6], 0.f),
                                  fmaxf(bv1.w + di * accf[7], 0.f)));
      *(uint4*)&As[row * SP + l8 * 8] = o;
    });
  }
  __syncthreads();

  const int l15 = lane & 15;
  const int quad = lane >> 4;
  half8 afrag[2];
#pragma unroll
  for (int s = 0; s < 2; ++s)
    afrag[s] = *(const half8*)&As[(w * 16 + l15) * SP + s * 32 + quad * 8];

  floatx4 acc[4];
#pragma unroll
  for (int t = 0; t < 4; ++t) acc[t] = (floatx4){0.f, 0.f, 0.f, 0.f};
#pragma unroll
  for (int s = 0; s < 2; ++s) {
#pragma unroll
    for (int t = 0; t < 4; ++t) {
      half8 bfrag = *(const half8*)&Wl[(t * 16 + l15) * SP + s * 32 + quad * 8];
      acc[t] = __builtin_amdgcn_mfma_f32_16x16x32_f16(afrag[s], bfrag, acc[t], 0, 0, 0);
    }
  }

#pragma unroll
  for (int r = 0; r < 4; ++r) {
    long node = blockBase + w * 16 + quad * 4 + r;
    if (node < n) {
      float dv = dinv[node];
#pragma unroll
      for (int t = 0; t < 4; ++t)
        hs1[node * 64 + t * 16 + l15] = __float2half(acc[t][r] * dv);
    }
  }
}

// h2s[node] = dinv[node] * ( relu(b1 + di*acc) . W2 )   (pre-scaled for layer 2)
__global__ __launch_bounds__(256) void k_gather64x8_dot(const __half* __restrict__ hs,
                                                        const int* __restrict__ ell,
                                                        const int* __restrict__ cnt,
                                                        const float* __restrict__ dinv,
                                                        const float* __restrict__ b1,
                                                        const float* __restrict__ W2,
                                                        float* __restrict__ h2s, int n) {
  if (blockIdx.x == 0 && threadIdx.x == 0) h2s[n] = 0.f;
  const int wave = (blockIdx.x * 256 + threadIdx.x) >> 6;
  gather8_one(wave, hs, ell, cnt, dinv, n, threadIdx.x & 63,
              [&](const float (&accf)[8], float di, int node, int l8, bool alive) {
    float4 bv0 = *(const float4*)&b1[l8 * 8];
    float4 bv1 = *(const float4*)&b1[l8 * 8 + 4];
    float4 wv0 = *(const float4*)&W2[l8 * 8];
    float4 wv1 = *(const float4*)&W2[l8 * 8 + 4];
    float part = fmaxf(bv0.x + di * accf[0], 0.f) * wv0.x;
    part = fmaf(fmaxf(bv0.y + di * accf[1], 0.f), wv0.y, part);
    part = fmaf(fmaxf(bv0.z + di * accf[2], 0.f), wv0.z, part);
    part = fmaf(fmaxf(bv0.w + di * accf[3], 0.f), wv0.w, part);
    part = fmaf(fmaxf(bv1.x + di * accf[4], 0.f), wv1.x, part);
    part = fmaf(fmaxf(bv1.y + di * accf[5], 0.f), wv1.y, part);
    part = fmaf(fmaxf(bv1.z + di * accf[6], 0.f), wv1.z, part);
    part = fmaf(fmaxf(bv1.w + di * accf[7], 0.f), wv1.w, part);
#pragma unroll
    for (int off = 1; off < 8; off <<= 1) part += __shfl_xor(part, off, 8);
    if (alive && l8 == 0) h2s[node] = di * part;
  });
}

// ---- dim-1 gather + MLP head fused, x8 ----

__global__ __launch_bounds__(256) void k_gather1_mlp_x8(const float* __restrict__ h2s,
                                                        const int* __restrict__ ell,
                                                        const int* __restrict__ cnt,
                                                        const float* __restrict__ dinv,
                                                        const float* __restrict__ b2,
                                                        const float* __restrict__ Wm1,
                                                        const float* __restrict__ bm1,
                                                        const float* __restrict__ Wm2,
                                                        const float* __restrict__ bm2,
                                                        float* __restrict__ out, int n) {
  __shared__ float w1s[64], w2s[64], b1s[64];
  if (threadIdx.x < 64) {
    w1s[threadIdx.x] = Wm1[threadIdx.x];
    w2s[threadIdx.x] = Wm2[threadIdx.x];
    b1s[threadIdx.x] = bm1[threadIdx.x];
  }
  __syncthreads();
  const int tid = threadIdx.x;
  const int lane = tid & 63;
  const int l8 = lane & 7;
  const int wave = (blockIdx.x * 256 + tid) >> 6;
  const int node = wave * 8 + (lane >> 3);
  const bool alive = node < n;
  const int nd = alive ? node : 0;
  const int c = alive ? cnt[nd] : 0;
  const float di = alive ? dinv[nd] : 0.f;
  const int* row = &ell[(long)nd * ELL_CAP];

  int cm = c;
  cm = max(cm, __shfl_xor(cm, 8, 64));
  cm = max(cm, __shfl_xor(cm, 16, 64));
  cm = max(cm, __shfl_xor(cm, 32, 64));
  const int nph = (cm + 7) >> 3;

  float acc = (alive && l8 == 0) ? h2s[nd] : 0.f;
  for (int ph = 0; ph < nph; ++ph) {
    int j = ph * 8 + l8;
    int s = (j < c) ? row[j] : n;
    acc += h2s[s];
  }
#pragma unroll
  for (int off = 1; off < 8; off <<= 1) acc += __shfl_xor(acc, off, 8);

  const float sv = b2[0] + di * acc;
  float o = 0.f;
#pragma unroll
  for (int q = 0; q < 8; ++q) {
    int j = l8 * 8 + q;
    o = fmaf(fmaxf(fmaf(sv, w1s[j], b1s[j]), 0.f), w2s[j], o);
  }
#pragma unroll
  for (int off = 1; off < 8; off <<= 1) o += __shfl_xor(o, off, 8);
  if (alive && l8 == 0) out[nd] = o + bm2[0];
}

// ---------------- launch ----------------
// R9: revert R8's atomic scatter (86-90us — cross-XCD sub-line writes).
// R1 pipeline + transposed hist_g (coalesced block-exclusive writes) +
// int4-vectorized edge loads. Ledger: gathers ~48, gemm0 ~10 (HBM floor),
// preprocessing ~22->~17 target, mlp ~4, harness-fixed ~109 (untouchable).

extern "C" void kernel_launch(void* const* d_in, const int* in_sizes, int n_in,
                              void* d_out, int out_size, void* d_ws, size_t ws_size,
                              hipStream_t stream) {
  const float* x   = (const float*)d_in[0];
  const int*   ei  = (const int*)d_in[1];
  const float* W0  = (const float*)d_in[2];
  const float* b0  = (const float*)d_in[3];
  const float* W1  = (const float*)d_in[4];
  const float* b1  = (const float*)d_in[5];
  const float* W2  = (const float*)d_in[6];
  const float* b2  = (const float*)d_in[7];
  const float* Wm1 = (const float*)d_in[8];
  const float* bm1 = (const float*)d_in[9];
  const float* Wm2 = (const float*)d_in[10];
  const float* bm2 = (const float*)d_in[11];

  const int n = in_sizes[0] / 128;  // 100000
  const int E = in_sizes[1] / 2;    // 1200000
  const int* src = ei;
  const int* dst = ei + E;

  float*  ws   = (float*)d_ws;
  float*  dinv = ws;                                   // n floats
  int*    cnt  = (int*)(ws + n);                       // n ints
  int*    ell  = cnt + n;                              // 48n ints
  __half* bufA = (__half*)(ell + (size_t)n * ELL_CAP); // (n+1)*64 halves (hs0)
  __half* bufB = bufA + (size_t)(n + 1) * 64;          // (n+1)*64 halves (hs1)
  float*  h2s  = (float*)(bufB + (size_t)(n + 1) * 64);// n+1 floats
  int*    hist_g = (int*)(h2s + (n + 1));              // SLB*NBUCK ints
  int*    buckets = (int*)bufA;                        // alias; dead before GEMM0

  const int g8b = (((n + 7) / 8) + 3) / 4;
  const int mfb = (n + 63) / 64;

  k_bucket<<<SLB, 1024, 0, stream>>>(src, dst, hist_g, buckets, E);
  k_ellbuild<<<NBUCK, 512, 0, stream>>>(buckets, hist_g, cnt, ell, dinv, n);

  k_gemm_mfma128<<<mfb, 256, 0, stream>>>(x, W0, dinv, bufA,
                                          bufA + (size_t)n * 64,
                                          bufB + (size_t)n * 64, n);

  k_gather_gemm<<<mfb, 256, 0, stream>>>(bufA, ell, cnt, dinv, b0, W1, bufB, n);

  k_gather64x8_dot<<<g8b, 256, 0, stream>>>(bufB, ell, cnt, dinv, b1, W2, h2s, n);

  k_gather1_mlp_x8<<<g8b, 256, 0, stream>>>(h2s, ell, cnt, dinv, b2, Wm1, bm1,
                                            Wm2, bm2, (float*)d_out, n);
}